// Round 1
// baseline (886.781 us; speedup 1.0000x reference)
//
#include <hip/hip_runtime.h>

#define BB 32
#define SS 4096
#define HH 1024
#define BS (BB * SS)

// Order-preserving float -> uint key (unsigned compare == float compare)
__device__ __forceinline__ unsigned fkey(float f) {
    unsigned u = __float_as_uint(f);
    return (u & 0x80000000u) ? ~u : (u | 0x80000000u);
}
__device__ __forceinline__ float funkey(unsigned k) {
    unsigned u = (k & 0x80000000u) ? (k ^ 0x80000000u) : ~k;
    return __uint_as_float(u);
}

// One wave (64 lanes) per (b,s) row: dot(x[row,:], W) + b.
// Block = 256 threads = 4 waves = 4 consecutive rows (same batch: 4 | 4096).
__global__ __launch_bounds__(256) void k_proj(
    const float* __restrict__ x, const int* __restrict__ mask,
    const float* __restrict__ W, const float* __restrict__ bvec,
    float* __restrict__ h, unsigned* __restrict__ mm)
{
    const int wave = threadIdx.x >> 6;
    const int lane = threadIdx.x & 63;
    const int row  = blockIdx.x * 4 + wave;

    const float4* xr = (const float4*)(x + (size_t)row * HH);
    const float4* Wv = (const float4*)W;

    float acc = 0.0f;
#pragma unroll
    for (int i = 0; i < 4; ++i) {
        float4 a = xr[i * 64 + lane];   // coalesced: 64 lanes x 16B = 1KB/instr
        float4 w = Wv[i * 64 + lane];   // L1-resident (4KB total)
        acc += a.x * w.x + a.y * w.y + a.z * w.z + a.w * w.w;
    }
#pragma unroll
    for (int off = 32; off >= 1; off >>= 1)
        acc += __shfl_xor(acc, off, 64);

    __shared__ unsigned smin[4], smax[4];
    if (lane == 0) {
        float hv = acc + bvec[0];
        h[row] = hv;
        bool m = (mask[row] != 0);
        unsigned k = fkey(hv);
        smin[wave] = m ? k : 0xFFFFFFFFu;
        smax[wave] = m ? k : 0u;
    }
    __syncthreads();
    if (threadIdx.x == 0) {
        unsigned mn = min(min(smin[0], smin[1]), min(smin[2], smin[3]));
        unsigned mx = max(max(smax[0], smax[1]), max(smax[2], smax[3]));
        const int batch = row >> 12;  // row / SS
        atomicMin(&mm[batch], mn);          // device-scope: XCD-safe
        atomicMax(&mm[BB + batch], mx);
    }
}

// out = mask ? (h - hmin)/(hmax - hmin) : 0   (mean/std cancel algebraically)
__global__ __launch_bounds__(256) void k_final(
    const float* __restrict__ h, const int* __restrict__ mask,
    const unsigned* __restrict__ mm, float* __restrict__ out)
{
    const int i = blockIdx.x * 256 + threadIdx.x;
    if (i >= BS) return;
    const int batch = i >> 12;
    const float hmin = funkey(mm[batch]);
    const float hmax = funkey(mm[BB + batch]);
    const float inv = 1.0f / (hmax - hmin);
    const float v = (h[i] - hmin) * inv;
    out[i] = (mask[i] != 0) ? v : 0.0f;
}

extern "C" void kernel_launch(void* const* d_in, const int* in_sizes, int n_in,
                              void* d_out, int out_size, void* d_ws, size_t ws_size,
                              hipStream_t stream) {
    const float* x    = (const float*)d_in[0];
    const int*   mask = (const int*)d_in[1];
    const float* W    = (const float*)d_in[2];
    const float* bv   = (const float*)d_in[3];
    float* out = (float*)d_out;

    float*    h  = (float*)d_ws;                                   // BS floats
    unsigned* mm = (unsigned*)((char*)d_ws + (size_t)BS * 4);      // 2*BB uints

    // Init min slots to uint-max (0xFF bytes), max slots to 0 — ws is poisoned.
    hipMemsetAsync(mm, 0xFF, BB * sizeof(unsigned), stream);
    hipMemsetAsync(mm + BB, 0x00, BB * sizeof(unsigned), stream);

    k_proj<<<BS / 4, 256, 0, stream>>>(x, mask, W, bv, h, mm);
    k_final<<<(BS + 255) / 256, 256, 0, stream>>>(h, mask, mm, out);
}

// Round 2
// 714.071 us; speedup vs baseline: 1.2419x; 1.2419x over previous
//
#include <hip/hip_runtime.h>

#define BB 32
#define SS 4096
#define HH 1024
#define BS (BB * SS)
#define WPB 256                 // waves per batch
#define RPW (SS / WPB)          // rows per wave = 16
#define NWAVES (BB * WPB)       // 8192 waves
#define NBLOCKS (NWAVES / 4)    // 2048 blocks of 256

// Order-preserving float -> uint key (unsigned compare == float compare)
__device__ __forceinline__ unsigned fkey(float f) {
    unsigned u = __float_as_uint(f);
    return (u & 0x80000000u) ? ~u : (u | 0x80000000u);
}
__device__ __forceinline__ float funkey(unsigned k) {
    unsigned u = (k & 0x80000000u) ? (k ^ 0x80000000u) : ~k;
    return __uint_as_float(u);
}
__device__ __forceinline__ float dot4(float4 a, float4 w) {
    return a.x * w.x + a.y * w.y + a.z * w.z + a.w * w.w;
}

// Persistent waves: each wave computes h for RPW rows of one batch,
// software-pipelined (prefetch row k+1 during row k's reduction).
// W lives in registers; no barriers; one atomic pair per wave.
__global__ __launch_bounds__(256) void k_proj(
    const float* __restrict__ x, const int* __restrict__ mask,
    const float* __restrict__ W, const float* __restrict__ bvec,
    float* __restrict__ h, unsigned* __restrict__ mm)
{
    const int lane  = threadIdx.x & 63;
    const int gw    = blockIdx.x * 4 + (threadIdx.x >> 6);
    const int batch = gw >> 8;          // gw / WPB
    const int r0    = gw & (WPB - 1);   // starting row in batch

    const float4* Wv = (const float4*)W;
    const float4 w0 = Wv[lane], w1 = Wv[64 + lane],
                 w2 = Wv[128 + lane], w3 = Wv[192 + lane];
    const float bval = bvec[0];

    const size_t rowBase = (size_t)batch * SS;
    unsigned kmin = 0xFFFFFFFFu, kmax = 0u;

    // prefetch first row
    const float4* xr = (const float4*)(x + (rowBase + r0) * HH);
    float4 a0 = xr[lane], a1 = xr[64 + lane], a2 = xr[128 + lane], a3 = xr[192 + lane];

    for (int k = 0; k < RPW; ++k) {
        const int r = r0 + k * WPB;
        float4 b0, b1, b2, b3;
        if (k < RPW - 1) {  // issue next row's loads before this row's reduce
            const float4* xn = (const float4*)(x + (rowBase + r + WPB) * HH);
            b0 = xn[lane]; b1 = xn[64 + lane]; b2 = xn[128 + lane]; b3 = xn[192 + lane];
        }
        float acc = dot4(a0, w0) + dot4(a1, w1) + dot4(a2, w2) + dot4(a3, w3);
#pragma unroll
        for (int off = 32; off >= 1; off >>= 1)
            acc += __shfl_xor(acc, off, 64);   // full sum in ALL lanes
        const float hv = acc + bval;
        if (lane == 0) h[rowBase + r] = hv;
        if (mask[rowBase + r] != 0) {          // wave-uniform broadcast load
            const unsigned key = fkey(hv);
            kmin = min(kmin, key); kmax = max(kmax, key);
        }
        a0 = b0; a1 = b1; a2 = b2; a3 = b3;
    }
    if (lane == 0) {
        atomicMin(&mm[batch], kmin);        // device-scope: XCD-safe
        atomicMax(&mm[BB + batch], kmax);
    }
}

// out = mask ? (h - hmin)/(hmax - hmin) : 0   (mean/std cancel algebraically)
__global__ __launch_bounds__(256) void k_final(
    const float* __restrict__ h, const int* __restrict__ mask,
    const unsigned* __restrict__ mm, float* __restrict__ out)
{
    const int i = blockIdx.x * 256 + threadIdx.x;
    if (i >= BS) return;
    const int batch = i >> 12;
    const float hmin = funkey(mm[batch]);
    const float hmax = funkey(mm[BB + batch]);
    const float inv = 1.0f / (hmax - hmin);
    const float v = (h[i] - hmin) * inv;
    out[i] = (mask[i] != 0) ? v : 0.0f;
}

extern "C" void kernel_launch(void* const* d_in, const int* in_sizes, int n_in,
                              void* d_out, int out_size, void* d_ws, size_t ws_size,
                              hipStream_t stream) {
    const float* x    = (const float*)d_in[0];
    const int*   mask = (const int*)d_in[1];
    const float* W    = (const float*)d_in[2];
    const float* bv   = (const float*)d_in[3];
    float* out = (float*)d_out;

    float*    h  = (float*)d_ws;                                   // BS floats
    unsigned* mm = (unsigned*)((char*)d_ws + (size_t)BS * 4);      // 2*BB uints

    hipMemsetAsync(mm, 0xFF, BB * sizeof(unsigned), stream);       // min slots
    hipMemsetAsync(mm + BB, 0x00, BB * sizeof(unsigned), stream);  // max slots

    k_proj<<<NBLOCKS, 256, 0, stream>>>(x, mask, W, bv, h, mm);
    k_final<<<(BS + 255) / 256, 256, 0, stream>>>(h, mask, mm, out);
}